// Round 1
// baseline (50519.553 us; speedup 1.0000x reference)
//
#include <hip/hip_runtime.h>
#include <hip/hip_bf16.h>
#include <math.h>

#define T_STEPS 1024
#define HDIM    1024
#define SDIM    4096
#define NBLK    256

__device__ __forceinline__ float sigmoidf_(float x) { return 1.0f / (1.0f + expf(-x)); }

// ---------------------------------------------------------------------------
// GEMM: C[M][N] = X[M][K] @ W[N][K]^T + (b1[N] + b2[N])
// 64x64 tile, BK=16, 256 threads, 4x4 register blocking.
// ---------------------------------------------------------------------------
__global__ __launch_bounds__(256) void gemm_xg(
    const float* __restrict__ X, const float* __restrict__ W,
    const float* __restrict__ b1, const float* __restrict__ b2,
    float* __restrict__ C, int M, int N, int K)
{
    __shared__ float As[16][64];
    __shared__ float Bs[16][64];
    const int tid = threadIdx.x;
    const int m0 = blockIdx.y * 64, n0 = blockIdx.x * 64;
    const int tx = tid & 15, ty = tid >> 4;
    const int lr = tid >> 2, ls = (tid & 3) << 2;
    float acc[4][4] = {};

    for (int kt = 0; kt < K; kt += 16) {
        const float4 xa = *(const float4*)(X + (size_t)(m0 + lr) * K + kt + ls);
        const float4 wb = *(const float4*)(W + (size_t)(n0 + lr) * K + kt + ls);
        __syncthreads();  // protect previous iteration's LDS reads
        As[ls + 0][lr] = xa.x; As[ls + 1][lr] = xa.y; As[ls + 2][lr] = xa.z; As[ls + 3][lr] = xa.w;
        Bs[ls + 0][lr] = wb.x; Bs[ls + 1][lr] = wb.y; Bs[ls + 2][lr] = wb.z; Bs[ls + 3][lr] = wb.w;
        __syncthreads();
#pragma unroll
        for (int k = 0; k < 16; ++k) {
            const float4 a = *(const float4*)&As[k][ty << 2];
            const float4 b = *(const float4*)&Bs[k][tx << 2];
            acc[0][0] += a.x * b.x; acc[0][1] += a.x * b.y; acc[0][2] += a.x * b.z; acc[0][3] += a.x * b.w;
            acc[1][0] += a.y * b.x; acc[1][1] += a.y * b.y; acc[1][2] += a.y * b.z; acc[1][3] += a.y * b.w;
            acc[2][0] += a.z * b.x; acc[2][1] += a.z * b.y; acc[2][2] += a.z * b.z; acc[2][3] += a.z * b.w;
            acc[3][0] += a.w * b.x; acc[3][1] += a.w * b.y; acc[3][2] += a.w * b.z; acc[3][3] += a.w * b.w;
        }
    }
    const int gn = n0 + (tx << 2);
    const float4 bias = make_float4(b1[gn + 0] + b2[gn + 0], b1[gn + 1] + b2[gn + 1],
                                    b1[gn + 2] + b2[gn + 2], b1[gn + 3] + b2[gn + 3]);
#pragma unroll
    for (int i = 0; i < 4; ++i) {
        float4 o = make_float4(acc[i][0] + bias.x, acc[i][1] + bias.y,
                               acc[i][2] + bias.z, acc[i][3] + bias.w);
        *(float4*)(C + (size_t)(m0 + (ty << 2) + i) * N + gn) = o;
    }
}

// ---------------------------------------------------------------------------
// Persistent LSTM scan. 256 blocks x 256 threads (4 waves). Wave w of block b
// owns output column j = b*4+w: gate rows j, j+H, j+2H, j+3H of w_hh,
// preloaded into registers (64 floats/lane). Per step: read full h (prev ys
// row), 64 FMA + 6-level butterfly x4 gates, gate math, write 1 float,
// device-wide flag barrier (per-block monotonic progress counters).
// ---------------------------------------------------------------------------
__global__ __launch_bounds__(256) void lstm_scan(
    const float* __restrict__ xg,     // [T][4H], bias already added
    const float* __restrict__ w_hh,   // [4H][H]
    const float* __restrict__ h0, const float* __restrict__ c0,
    float* __restrict__ ys,           // [T][H]
    float* __restrict__ hN, float* __restrict__ cN,
    unsigned int* prog)               // [NBLK], zeroed before launch
{
    const int tid = threadIdx.x, lane = tid & 63, wv = tid >> 6;
    const int j = (blockIdx.x << 2) + wv;

    const float4* r0 = (const float4*)(w_hh + (size_t)j * HDIM);
    const float4* r1 = (const float4*)(w_hh + (size_t)(j + HDIM) * HDIM);
    const float4* r2 = (const float4*)(w_hh + (size_t)(j + 2 * HDIM) * HDIM);
    const float4* r3 = (const float4*)(w_hh + (size_t)(j + 3 * HDIM) * HDIM);
    float4 w0[4], w1[4], w2[4], w3[4];
#pragma unroll
    for (int k = 0; k < 4; ++k) {
        const int idx = lane + (k << 6);
        w0[k] = r0[idx]; w1[k] = r1[idx]; w2[k] = r2[idx]; w3[k] = r3[idx];
    }
    float c = c0[j];
    float h_out = 0.0f;

    for (int t = 0; t < T_STEPS; ++t) {
        if (t > 0) {
            // wait until every block published ys[t-1]
            while (__hip_atomic_load(&prog[tid], __ATOMIC_RELAXED, __HIP_MEMORY_SCOPE_AGENT) < (unsigned)t)
                __builtin_amdgcn_s_sleep(1);
            __threadfence();     // acquire fence (agent scope)
            __syncthreads();     // block-wide: all flags observed
        }
        const float4* hp = (t == 0) ? (const float4*)h0
                                    : (const float4*)(ys + (size_t)(t - 1) * HDIM);
        float gi = 0.f, gf = 0.f, gg = 0.f, go = 0.f;
#pragma unroll
        for (int k = 0; k < 4; ++k) {
            const int idx = lane + (k << 6);
            const float4 hv = hp[idx];
            gi += w0[k].x * hv.x + w0[k].y * hv.y + w0[k].z * hv.z + w0[k].w * hv.w;
            gf += w1[k].x * hv.x + w1[k].y * hv.y + w1[k].z * hv.z + w1[k].w * hv.w;
            gg += w2[k].x * hv.x + w2[k].y * hv.y + w2[k].z * hv.z + w2[k].w * hv.w;
            go += w3[k].x * hv.x + w3[k].y * hv.y + w3[k].z * hv.z + w3[k].w * hv.w;
        }
#pragma unroll
        for (int d = 32; d > 0; d >>= 1) {
            gi += __shfl_xor(gi, d, 64);
            gf += __shfl_xor(gf, d, 64);
            gg += __shfl_xor(gg, d, 64);
            go += __shfl_xor(go, d, 64);
        }
        const float* xgt = xg + (size_t)t * (4 * HDIM);
        gi += xgt[j]; gf += xgt[j + HDIM]; gg += xgt[j + 2 * HDIM]; go += xgt[j + 3 * HDIM];

        const float ig = sigmoidf_(gi), fg = sigmoidf_(gf), og = sigmoidf_(go);
        const float gv = tanhf(gg);
        c = fg * c + ig * gv;
        h_out = og * tanhf(c);
        if (lane == 0) ys[(size_t)t * HDIM + j] = h_out;

        __syncthreads();         // all waves of this block wrote ys[t]
        if (tid == 0) {
            __threadfence();     // release: make ys[t] agent-visible
            __hip_atomic_store(&prog[blockIdx.x], (unsigned)(t + 1),
                               __ATOMIC_RELAXED, __HIP_MEMORY_SCOPE_AGENT);
        }
    }
    if (lane == 0) { hN[j] = h_out; cN[j] = c; }
}

// ---------------------------------------------------------------------------
// Attention
// ---------------------------------------------------------------------------
__global__ __launch_bounds__(256) void attn_scores(
    const float* __restrict__ enc, const float* __restrict__ tgt,
    float* __restrict__ scores)
{
    const int lane = threadIdx.x & 63, wv = threadIdx.x >> 6;
    const int s = (blockIdx.x << 2) + wv;
    const float4* e4 = (const float4*)(enc + (size_t)s * HDIM);
    const float4* t4 = (const float4*)tgt;
    float acc = 0.f;
#pragma unroll
    for (int k = 0; k < 4; ++k) {
        const int idx = lane + (k << 6);
        const float4 e = e4[idx], t = t4[idx];
        acc += e.x * t.x + e.y * t.y + e.z * t.z + e.w * t.w;
    }
#pragma unroll
    for (int d = 32; d > 0; d >>= 1) acc += __shfl_xor(acc, d, 64);
    if (lane == 0) scores[s] = acc;
}

__global__ __launch_bounds__(1024) void attn_softmax(
    const float* __restrict__ scores, float* __restrict__ wts)
{
    __shared__ float rmax[16];
    __shared__ float rsum[16];
    const int tid = threadIdx.x, lane = tid & 63, wv = tid >> 6;
    const float4 v = ((const float4*)scores)[tid];
    float m = fmaxf(fmaxf(v.x, v.y), fmaxf(v.z, v.w));
#pragma unroll
    for (int d = 32; d > 0; d >>= 1) m = fmaxf(m, __shfl_xor(m, d, 64));
    if (lane == 0) rmax[wv] = m;
    __syncthreads();
    float gm = rmax[0];
#pragma unroll
    for (int i = 1; i < 16; ++i) gm = fmaxf(gm, rmax[i]);
    const float e0 = expf(v.x - gm), e1 = expf(v.y - gm), e2 = expf(v.z - gm), e3 = expf(v.w - gm);
    float s = e0 + e1 + e2 + e3;
#pragma unroll
    for (int d = 32; d > 0; d >>= 1) s += __shfl_xor(s, d, 64);
    if (lane == 0) rsum[wv] = s;
    __syncthreads();
    float gs = 0.f;
#pragma unroll
    for (int i = 0; i < 16; ++i) gs += rsum[i];
    const float inv = 1.0f / gs;
    ((float4*)wts)[tid] = make_float4(e0 * inv, e1 * inv, e2 * inv, e3 * inv);
}

__global__ __launch_bounds__(256) void attn_context(
    const float* __restrict__ wts, const float* __restrict__ enc,
    float* __restrict__ ctx)
{
    __shared__ float red[16][16];
    const int ci = threadIdx.x & 15, ri = threadIdx.x >> 4;
    const int col = blockIdx.x * 16 + ci;
    float acc = 0.f;
    for (int r = ri; r < SDIM; r += 16)
        acc += wts[r] * enc[(size_t)r * HDIM + col];
    red[ri][ci] = acc;
    __syncthreads();
    if (ri == 0) {
        float s = 0.f;
#pragma unroll
        for (int k = 0; k < 16; ++k) s += red[k][ci];
        ctx[col] = s;
    }
}

__global__ __launch_bounds__(256) void attn_final(
    const float* __restrict__ ctx, const float* __restrict__ h2,
    const float* __restrict__ w_cat, const float* __restrict__ b_cat,
    float* __restrict__ out)
{
    const int lane = threadIdx.x & 63, wv = threadIdx.x >> 6;
    const int j = (blockIdx.x << 2) + wv;
    const float4* wc1 = (const float4*)(w_cat + (size_t)j * 2048);
    const float4* wc2 = (const float4*)(w_cat + (size_t)j * 2048 + 1024);
    const float4* c4 = (const float4*)ctx;
    const float4* h4 = (const float4*)h2;
    float acc = 0.f;
#pragma unroll
    for (int k = 0; k < 4; ++k) {
        const int idx = lane + (k << 6);
        float4 a = wc1[idx], b = c4[idx];
        acc += a.x * b.x + a.y * b.y + a.z * b.z + a.w * b.w;
        a = wc2[idx]; b = h4[idx];
        acc += a.x * b.x + a.y * b.y + a.z * b.z + a.w * b.w;
    }
#pragma unroll
    for (int d = 32; d > 0; d >>= 1) acc += __shfl_xor(acc, d, 64);
    if (lane == 0) out[j] = tanhf(acc + b_cat[j]);
}

// ---------------------------------------------------------------------------
extern "C" void kernel_launch(void* const* d_in, const int* in_sizes, int n_in,
                              void* d_out, int out_size, void* d_ws, size_t ws_size,
                              hipStream_t stream)
{
    (void)in_sizes; (void)n_in; (void)out_size; (void)ws_size;
    const float* x     = (const float*)d_in[0];
    const float* enc   = (const float*)d_in[1];
    const float* h0all = (const float*)d_in[2];
    const float* c0all = (const float*)d_in[3];
    const float* w_ih0 = (const float*)d_in[4];
    const float* w_hh0 = (const float*)d_in[5];
    const float* b_ih0 = (const float*)d_in[6];
    const float* b_hh0 = (const float*)d_in[7];
    const float* w_ih1 = (const float*)d_in[8];
    const float* w_hh1 = (const float*)d_in[9];
    const float* b_ih1 = (const float*)d_in[10];
    const float* b_hh1 = (const float*)d_in[11];
    const float* w_cat = (const float*)d_in[12];
    const float* b_cat = (const float*)d_in[13];
    float* out = (float*)d_out;

    float* ws = (float*)d_ws;
    float* xg     = ws;                       // 1024*4096 = 4,194,304 floats
    float* out0   = ws + 4194304;             // 1024*1024 = 1,048,576
    float* scores = ws + 4194304 + 1048576;   // 4096
    float* wts    = scores + 4096;            // 4096
    float* ctx    = wts + 4096;               // 1024
    unsigned int* prog = (unsigned int*)(ctx + 1024);  // 512 uints

    float* out1 = out;                 // [1024][1024]
    float* hN   = out + 1048576;       // h1, h2
    float* cN   = out + 1050624;       // c1, c2
    float* attn = out + 1052672;       // 1024

    hipMemsetAsync(prog, 0, 512 * sizeof(unsigned int), stream);

    dim3 gg(64, 16);  // N/64, M/64
    gemm_xg<<<gg, 256, 0, stream>>>(x, w_ih0, b_ih0, b_hh0, xg, 1024, 4096, 1024);
    lstm_scan<<<NBLK, 256, 0, stream>>>(xg, w_hh0, h0all, c0all, out0, hN, cN, prog);
    gemm_xg<<<gg, 256, 0, stream>>>(out0, w_ih1, b_ih1, b_hh1, xg, 1024, 4096, 1024);
    lstm_scan<<<NBLK, 256, 0, stream>>>(xg, w_hh1, h0all + 1024, c0all + 1024,
                                        out1, hN + 1024, cN + 1024, prog + 256);
    attn_scores<<<1024, 256, 0, stream>>>(enc, hN + 1024, scores);
    attn_softmax<<<1, 1024, 0, stream>>>(scores, wts);
    attn_context<<<64, 256, 0, stream>>>(wts, enc, ctx);
    attn_final<<<256, 256, 0, stream>>>(ctx, hN + 1024, w_cat, b_cat, attn);
}

// Round 2
// 13468.729 us; speedup vs baseline: 3.7509x; 3.7509x over previous
//
#include <hip/hip_runtime.h>
#include <hip/hip_bf16.h>
#include <math.h>

#define T_STEPS 1024
#define HDIM    1024
#define SDIM    4096
#define NBLK    256

__device__ __forceinline__ float sigmoidf_(float x) { return 1.0f / (1.0f + expf(-x)); }

// ---------------------------------------------------------------------------
// GEMM: C[M][N] = X[M][K] @ W[N][K]^T + (b1[N] + b2[N])
// 64x64 tile, BK=16, 256 threads, 4x4 register blocking.
// ---------------------------------------------------------------------------
__global__ __launch_bounds__(256) void gemm_xg(
    const float* __restrict__ X, const float* __restrict__ W,
    const float* __restrict__ b1, const float* __restrict__ b2,
    float* __restrict__ C, int M, int N, int K)
{
    __shared__ float As[16][64];
    __shared__ float Bs[16][64];
    const int tid = threadIdx.x;
    const int m0 = blockIdx.y * 64, n0 = blockIdx.x * 64;
    const int tx = tid & 15, ty = tid >> 4;
    const int lr = tid >> 2, ls = (tid & 3) << 2;
    float acc[4][4] = {};

    for (int kt = 0; kt < K; kt += 16) {
        const float4 xa = *(const float4*)(X + (size_t)(m0 + lr) * K + kt + ls);
        const float4 wb = *(const float4*)(W + (size_t)(n0 + lr) * K + kt + ls);
        __syncthreads();  // protect previous iteration's LDS reads
        As[ls + 0][lr] = xa.x; As[ls + 1][lr] = xa.y; As[ls + 2][lr] = xa.z; As[ls + 3][lr] = xa.w;
        Bs[ls + 0][lr] = wb.x; Bs[ls + 1][lr] = wb.y; Bs[ls + 2][lr] = wb.z; Bs[ls + 3][lr] = wb.w;
        __syncthreads();
#pragma unroll
        for (int k = 0; k < 16; ++k) {
            const float4 a = *(const float4*)&As[k][ty << 2];
            const float4 b = *(const float4*)&Bs[k][tx << 2];
            acc[0][0] += a.x * b.x; acc[0][1] += a.x * b.y; acc[0][2] += a.x * b.z; acc[0][3] += a.x * b.w;
            acc[1][0] += a.y * b.x; acc[1][1] += a.y * b.y; acc[1][2] += a.y * b.z; acc[1][3] += a.y * b.w;
            acc[2][0] += a.z * b.x; acc[2][1] += a.z * b.y; acc[2][2] += a.z * b.z; acc[2][3] += a.z * b.w;
            acc[3][0] += a.w * b.x; acc[3][1] += a.w * b.y; acc[3][2] += a.w * b.z; acc[3][3] += a.w * b.w;
        }
    }
    const int gn = n0 + (tx << 2);
    const float4 bias = make_float4(b1[gn + 0] + b2[gn + 0], b1[gn + 1] + b2[gn + 1],
                                    b1[gn + 2] + b2[gn + 2], b1[gn + 3] + b2[gn + 3]);
#pragma unroll
    for (int i = 0; i < 4; ++i) {
        float4 o = make_float4(acc[i][0] + bias.x, acc[i][1] + bias.y,
                               acc[i][2] + bias.z, acc[i][3] + bias.w);
        *(float4*)(C + (size_t)(m0 + (ty << 2) + i) * N + gn) = o;
    }
}

// ---------------------------------------------------------------------------
// Persistent LSTM scan — FENCE-FREE cross-block sync.
// All cross-block traffic (h values + per-wave progress flags) uses relaxed
// AGENT-scope atomics => sc0/sc1 cache-bypass accesses serviced at the
// coherent point. No __threadfence (no buffer_wbl2/buffer_inv L2 flushes).
// Producer ordering: ys store -> s_waitcnt vmcnt(0) -> flag store.
// Consumer: poll 4 flags/thread (256 threads cover 1024 wave-flags) ->
// __syncthreads joins observations -> bypassing loads of h.
// xg[t] gate biases prefetched (cached loads) BEFORE the poll loop.
// ---------------------------------------------------------------------------
__global__ __launch_bounds__(256) void lstm_scan(
    const float* __restrict__ xg,     // [T][4H], bias already added
    const float* __restrict__ w_hh,   // [4H][H]
    const float* __restrict__ h0, const float* __restrict__ c0,
    float* __restrict__ ys,           // [T][H]
    float* __restrict__ hN, float* __restrict__ cN,
    unsigned int* flags)              // [1024] per-wave flags, zeroed
{
    const int tid = threadIdx.x, lane = tid & 63, wv = tid >> 6;
    const int j = (blockIdx.x << 2) + wv;   // output column owned by this wave

    const float4* r0 = (const float4*)(w_hh + (size_t)j * HDIM);
    const float4* r1 = (const float4*)(w_hh + (size_t)(j + HDIM) * HDIM);
    const float4* r2 = (const float4*)(w_hh + (size_t)(j + 2 * HDIM) * HDIM);
    const float4* r3 = (const float4*)(w_hh + (size_t)(j + 3 * HDIM) * HDIM);
    float4 w0[4], w1[4], w2[4], w3[4];
#pragma unroll
    for (int k = 0; k < 4; ++k) {
        const int idx = lane + (k << 6);
        w0[k] = r0[idx]; w1[k] = r1[idx]; w2[k] = r2[idx]; w3[k] = r3[idx];
    }
    float c = c0[j];
    float h_out = 0.0f;

    for (int t = 0; t < T_STEPS; ++t) {
        // prefetch this step's gate biases (read-only, cached) before waiting
        const float* xgt = xg + (size_t)t * (4 * HDIM);
        const float xb_i = xgt[j];
        const float xb_f = xgt[j + HDIM];
        const float xb_g = xgt[j + 2 * HDIM];
        const float xb_o = xgt[j + 3 * HDIM];

        if (t > 0) {
            const unsigned want = (unsigned)t;
            for (;;) {
                const unsigned f0 = __hip_atomic_load(&flags[tid],       __ATOMIC_RELAXED, __HIP_MEMORY_SCOPE_AGENT);
                const unsigned f1 = __hip_atomic_load(&flags[tid + 256], __ATOMIC_RELAXED, __HIP_MEMORY_SCOPE_AGENT);
                const unsigned f2 = __hip_atomic_load(&flags[tid + 512], __ATOMIC_RELAXED, __HIP_MEMORY_SCOPE_AGENT);
                const unsigned f3 = __hip_atomic_load(&flags[tid + 768], __ATOMIC_RELAXED, __HIP_MEMORY_SCOPE_AGENT);
                if (f0 >= want && f1 >= want && f2 >= want && f3 >= want) break;
            }
            __syncthreads();   // all 4 waves observed all 1024 flags
        }

        const float* hsrc = (t == 0) ? h0 : ys + (size_t)(t - 1) * HDIM;
        // bypassing loads of h (16 floats/lane), layout matches weight frags
        float hv[4][4];
#pragma unroll
        for (int k = 0; k < 4; ++k) {
            const int base = 4 * (lane + (k << 6));
#pragma unroll
            for (int e = 0; e < 4; ++e)
                hv[k][e] = __hip_atomic_load(hsrc + base + e, __ATOMIC_RELAXED, __HIP_MEMORY_SCOPE_AGENT);
        }
        float gi = 0.f, gf = 0.f, gg = 0.f, go = 0.f;
#pragma unroll
        for (int k = 0; k < 4; ++k) {
            gi += w0[k].x * hv[k][0] + w0[k].y * hv[k][1] + w0[k].z * hv[k][2] + w0[k].w * hv[k][3];
            gf += w1[k].x * hv[k][0] + w1[k].y * hv[k][1] + w1[k].z * hv[k][2] + w1[k].w * hv[k][3];
            gg += w2[k].x * hv[k][0] + w2[k].y * hv[k][1] + w2[k].z * hv[k][2] + w2[k].w * hv[k][3];
            go += w3[k].x * hv[k][0] + w3[k].y * hv[k][1] + w3[k].z * hv[k][2] + w3[k].w * hv[k][3];
        }
#pragma unroll
        for (int d = 32; d > 0; d >>= 1) {
            gi += __shfl_xor(gi, d, 64);
            gf += __shfl_xor(gf, d, 64);
            gg += __shfl_xor(gg, d, 64);
            go += __shfl_xor(go, d, 64);
        }
        const float ig = sigmoidf_(gi + xb_i), fg = sigmoidf_(gf + xb_f), og = sigmoidf_(go + xb_o);
        const float gv = tanhf(gg + xb_g);
        c = fg * c + ig * gv;
        h_out = og * tanhf(c);

        if (lane == 0)
            __hip_atomic_store(ys + (size_t)t * HDIM + j, h_out, __ATOMIC_RELAXED, __HIP_MEMORY_SCOPE_AGENT);
        asm volatile("s_waitcnt vmcnt(0)" ::: "memory");  // data globally visible
        if (lane == 0)
            __hip_atomic_store(&flags[j], (unsigned)(t + 1), __ATOMIC_RELAXED, __HIP_MEMORY_SCOPE_AGENT);
        // no trailing __syncthreads: per-wave flags gate the next step
    }
    if (lane == 0) { hN[j] = h_out; cN[j] = c; }
}

// ---------------------------------------------------------------------------
// Attention
// ---------------------------------------------------------------------------
__global__ __launch_bounds__(256) void attn_scores(
    const float* __restrict__ enc, const float* __restrict__ tgt,
    float* __restrict__ scores)
{
    const int lane = threadIdx.x & 63, wv = threadIdx.x >> 6;
    const int s = (blockIdx.x << 2) + wv;
    const float4* e4 = (const float4*)(enc + (size_t)s * HDIM);
    const float4* t4 = (const float4*)tgt;
    float acc = 0.f;
#pragma unroll
    for (int k = 0; k < 4; ++k) {
        const int idx = lane + (k << 6);
        const float4 e = e4[idx], t = t4[idx];
        acc += e.x * t.x + e.y * t.y + e.z * t.z + e.w * t.w;
    }
#pragma unroll
    for (int d = 32; d > 0; d >>= 1) acc += __shfl_xor(acc, d, 64);
    if (lane == 0) scores[s] = acc;
}

__global__ __launch_bounds__(1024) void attn_softmax(
    const float* __restrict__ scores, float* __restrict__ wts)
{
    __shared__ float rmax[16];
    __shared__ float rsum[16];
    const int tid = threadIdx.x, lane = tid & 63, wv = tid >> 6;
    const float4 v = ((const float4*)scores)[tid];
    float m = fmaxf(fmaxf(v.x, v.y), fmaxf(v.z, v.w));
#pragma unroll
    for (int d = 32; d > 0; d >>= 1) m = fmaxf(m, __shfl_xor(m, d, 64));
    if (lane == 0) rmax[wv] = m;
    __syncthreads();
    float gm = rmax[0];
#pragma unroll
    for (int i = 1; i < 16; ++i) gm = fmaxf(gm, rmax[i]);
    const float e0 = expf(v.x - gm), e1 = expf(v.y - gm), e2 = expf(v.z - gm), e3 = expf(v.w - gm);
    float s = e0 + e1 + e2 + e3;
#pragma unroll
    for (int d = 32; d > 0; d >>= 1) s += __shfl_xor(s, d, 64);
    if (lane == 0) rsum[wv] = s;
    __syncthreads();
    float gs = 0.f;
#pragma unroll
    for (int i = 0; i < 16; ++i) gs += rsum[i];
    const float inv = 1.0f / gs;
    ((float4*)wts)[tid] = make_float4(e0 * inv, e1 * inv, e2 * inv, e3 * inv);
}

__global__ __launch_bounds__(256) void attn_context(
    const float* __restrict__ wts, const float* __restrict__ enc,
    float* __restrict__ ctx)
{
    __shared__ float red[16][16];
    const int ci = threadIdx.x & 15, ri = threadIdx.x >> 4;
    const int col = blockIdx.x * 16 + ci;
    float acc = 0.f;
    for (int r = ri; r < SDIM; r += 16)
        acc += wts[r] * enc[(size_t)r * HDIM + col];
    red[ri][ci] = acc;
    __syncthreads();
    if (ri == 0) {
        float s = 0.f;
#pragma unroll
        for (int k = 0; k < 16; ++k) s += red[k][ci];
        ctx[col] = s;
    }
}

__global__ __launch_bounds__(256) void attn_final(
    const float* __restrict__ ctx, const float* __restrict__ h2,
    const float* __restrict__ w_cat, const float* __restrict__ b_cat,
    float* __restrict__ out)
{
    const int lane = threadIdx.x & 63, wv = threadIdx.x >> 6;
    const int j = (blockIdx.x << 2) + wv;
    const float4* wc1 = (const float4*)(w_cat + (size_t)j * 2048);
    const float4* wc2 = (const float4*)(w_cat + (size_t)j * 2048 + 1024);
    const float4* c4 = (const float4*)ctx;
    const float4* h4 = (const float4*)h2;
    float acc = 0.f;
#pragma unroll
    for (int k = 0; k < 4; ++k) {
        const int idx = lane + (k << 6);
        float4 a = wc1[idx], b = c4[idx];
        acc += a.x * b.x + a.y * b.y + a.z * b.z + a.w * b.w;
        a = wc2[idx]; b = h4[idx];
        acc += a.x * b.x + a.y * b.y + a.z * b.z + a.w * b.w;
    }
#pragma unroll
    for (int d = 32; d > 0; d >>= 1) acc += __shfl_xor(acc, d, 64);
    if (lane == 0) out[j] = tanhf(acc + b_cat[j]);
}

// ---------------------------------------------------------------------------
extern "C" void kernel_launch(void* const* d_in, const int* in_sizes, int n_in,
                              void* d_out, int out_size, void* d_ws, size_t ws_size,
                              hipStream_t stream)
{
    (void)in_sizes; (void)n_in; (void)out_size; (void)ws_size;
    const float* x     = (const float*)d_in[0];
    const float* enc   = (const float*)d_in[1];
    const float* h0all = (const float*)d_in[2];
    const float* c0all = (const float*)d_in[3];
    const float* w_ih0 = (const float*)d_in[4];
    const float* w_hh0 = (const float*)d_in[5];
    const float* b_ih0 = (const float*)d_in[6];
    const float* b_hh0 = (const float*)d_in[7];
    const float* w_ih1 = (const float*)d_in[8];
    const float* w_hh1 = (const float*)d_in[9];
    const float* b_ih1 = (const float*)d_in[10];
    const float* b_hh1 = (const float*)d_in[11];
    const float* w_cat = (const float*)d_in[12];
    const float* b_cat = (const float*)d_in[13];
    float* out = (float*)d_out;

    float* ws = (float*)d_ws;
    float* xg     = ws;                       // 1024*4096 = 4,194,304 floats
    float* out0   = ws + 4194304;             // 1024*1024 = 1,048,576
    float* scores = ws + 4194304 + 1048576;   // 4096
    float* wts    = scores + 4096;            // 4096
    float* ctx    = wts + 4096;               // 1024
    unsigned int* flags = (unsigned int*)(ctx + 1024);  // 2048 uints (2 scans)

    float* out1 = out;                 // [1024][1024]
    float* hN   = out + 1048576;       // h1, h2
    float* cN   = out + 1050624;       // c1, c2
    float* attn = out + 1052672;       // 1024

    hipMemsetAsync(flags, 0, 2048 * sizeof(unsigned int), stream);

    dim3 gg(64, 16);  // N/64, M/64
    gemm_xg<<<gg, 256, 0, stream>>>(x, w_ih0, b_ih0, b_hh0, xg, 1024, 4096, 1024);
    lstm_scan<<<NBLK, 256, 0, stream>>>(xg, w_hh0, h0all, c0all, out0, hN, cN, flags);
    gemm_xg<<<gg, 256, 0, stream>>>(out0, w_ih1, b_ih1, b_hh1, xg, 1024, 4096, 1024);
    lstm_scan<<<NBLK, 256, 0, stream>>>(xg, w_hh1, h0all + 1024, c0all + 1024,
                                        out1, hN + 1024, cN + 1024, flags + 1024);
    attn_scores<<<1024, 256, 0, stream>>>(enc, hN + 1024, scores);
    attn_softmax<<<1, 1024, 0, stream>>>(scores, wts);
    attn_context<<<64, 256, 0, stream>>>(wts, enc, ctx);
    attn_final<<<256, 256, 0, stream>>>(ctx, hN + 1024, w_cat, b_cat, attn);
}

// Round 3
// 7340.279 us; speedup vs baseline: 6.8825x; 1.8349x over previous
//
#include <hip/hip_runtime.h>
#include <hip/hip_bf16.h>
#include <math.h>

#define T_STEPS 1024
#define HDIM    1024
#define SDIM    4096
#define NBLK    256

__device__ __forceinline__ float sigmoidf_(float x) { return 1.0f / (1.0f + expf(-x)); }

// ---------------------------------------------------------------------------
// GEMM: C[M][N] = X[M][K] @ W[N][K]^T + (b1[N] + b2[N])
// 64x64 tile, BK=16, 256 threads, 4x4 register blocking.
// ---------------------------------------------------------------------------
__global__ __launch_bounds__(256) void gemm_xg(
    const float* __restrict__ X, const float* __restrict__ W,
    const float* __restrict__ b1, const float* __restrict__ b2,
    float* __restrict__ C, int M, int N, int K)
{
    __shared__ float As[16][64];
    __shared__ float Bs[16][64];
    const int tid = threadIdx.x;
    const int m0 = blockIdx.y * 64, n0 = blockIdx.x * 64;
    const int tx = tid & 15, ty = tid >> 4;
    const int lr = tid >> 2, ls = (tid & 3) << 2;
    float acc[4][4] = {};

    for (int kt = 0; kt < K; kt += 16) {
        const float4 xa = *(const float4*)(X + (size_t)(m0 + lr) * K + kt + ls);
        const float4 wb = *(const float4*)(W + (size_t)(n0 + lr) * K + kt + ls);
        __syncthreads();  // protect previous iteration's LDS reads
        As[ls + 0][lr] = xa.x; As[ls + 1][lr] = xa.y; As[ls + 2][lr] = xa.z; As[ls + 3][lr] = xa.w;
        Bs[ls + 0][lr] = wb.x; Bs[ls + 1][lr] = wb.y; Bs[ls + 2][lr] = wb.z; Bs[ls + 3][lr] = wb.w;
        __syncthreads();
#pragma unroll
        for (int k = 0; k < 16; ++k) {
            const float4 a = *(const float4*)&As[k][ty << 2];
            const float4 b = *(const float4*)&Bs[k][tx << 2];
            acc[0][0] += a.x * b.x; acc[0][1] += a.x * b.y; acc[0][2] += a.x * b.z; acc[0][3] += a.x * b.w;
            acc[1][0] += a.y * b.x; acc[1][1] += a.y * b.y; acc[1][2] += a.y * b.z; acc[1][3] += a.y * b.w;
            acc[2][0] += a.z * b.x; acc[2][1] += a.z * b.y; acc[2][2] += a.z * b.z; acc[2][3] += a.z * b.w;
            acc[3][0] += a.w * b.x; acc[3][1] += a.w * b.y; acc[3][2] += a.w * b.z; acc[3][3] += a.w * b.w;
        }
    }
    const int gn = n0 + (tx << 2);
    const float4 bias = make_float4(b1[gn + 0] + b2[gn + 0], b1[gn + 1] + b2[gn + 1],
                                    b1[gn + 2] + b2[gn + 2], b1[gn + 3] + b2[gn + 3]);
#pragma unroll
    for (int i = 0; i < 4; ++i) {
        float4 o = make_float4(acc[i][0] + bias.x, acc[i][1] + bias.y,
                               acc[i][2] + bias.z, acc[i][3] + bias.w);
        *(float4*)(C + (size_t)(m0 + (ty << 2) + i) * N + gn) = o;
    }
}

// ---------------------------------------------------------------------------
// Persistent LSTM scan, v3.
//  - Fused data+flag: producer publishes u64 {tag:32 | h_bits:32} with ONE
//    relaxed agent-scope 8B store into a 2-row rotating buffer tag[2][1024].
//    Consumers poll the tag and get h in the same load: one MALL round trip.
//    W=2 rotation is safe: row (t+1)&1 is only overwritten after ALL columns
//    of step t are published, which implies every block finished its global
//    reads of step t-1 (reads happen before that block's step-t store).
//  - Only wave 0 polls (16 u64 loads covering all 1024 columns), writes h to
//    LDS; all 4 waves consume from LDS. One __syncthreads per step.
//  - __launch_bounds__(256,1): lift VGPR cap so the 64 weight floats/lane
//    stay register-resident (round-2 binary had VGPR=60 => weights reloaded
//    from L2 every step; that was most of the 6.2us/step).
//  - Tag ranges: layer0 writes 1..1024, layer1 writes 1025..2048; exact-
//    equality compare + 16KB memset per launch => no ABA across graph replays.
// ---------------------------------------------------------------------------
__global__ __launch_bounds__(256, 1) void lstm_scan(
    const float* __restrict__ xg,     // [T][4H], bias already added
    const float* __restrict__ w_hh,   // [4H][H]
    const float* __restrict__ h0, const float* __restrict__ c0,
    float* __restrict__ ys,           // [T][H] plain output (gemm/out1 input)
    float* __restrict__ hN, float* __restrict__ cN,
    unsigned long long* __restrict__ tagbuf,  // [2][1024], zeroed per launch
    unsigned tag_base)
{
    __shared__ float h_lds[HDIM];
    const int tid = threadIdx.x, lane = tid & 63, wv = tid >> 6;
    const int j = (blockIdx.x << 2) + wv;   // output column owned by this wave

    const float4* r0 = (const float4*)(w_hh + (size_t)j * HDIM);
    const float4* r1 = (const float4*)(w_hh + (size_t)(j + HDIM) * HDIM);
    const float4* r2 = (const float4*)(w_hh + (size_t)(j + 2 * HDIM) * HDIM);
    const float4* r3 = (const float4*)(w_hh + (size_t)(j + 3 * HDIM) * HDIM);
    float4 w0[4], w1[4], w2[4], w3[4];
#pragma unroll
    for (int k = 0; k < 4; ++k) {
        const int idx = lane + (k << 6);
        w0[k] = r0[idx]; w1[k] = r1[idx]; w2[k] = r2[idx]; w3[k] = r3[idx];
    }
    float c = c0[j];
    float h_out = 0.0f;

    for (int t = 0; t < T_STEPS; ++t) {
        // this step's gate biases: plain cached loads, overlap with the poll
        const float* xgt = xg + (size_t)t * (4 * HDIM);
        const float xb_i = xgt[j];
        const float xb_f = xgt[j + HDIM];
        const float xb_g = xgt[j + 2 * HDIM];
        const float xb_o = xgt[j + 3 * HDIM];

        if (wv == 0) {
            if (t == 0) {
#pragma unroll
                for (int q = 0; q < 16; ++q)
                    h_lds[lane + (q << 6)] = h0[lane + (q << 6)];
            } else {
                const unsigned long long* row = tagbuf + ((size_t)((t - 1) & 1) << 10);
                const unsigned want = tag_base + (unsigned)t;
                unsigned long long v[16];
                for (;;) {
#pragma unroll
                    for (int q = 0; q < 16; ++q)
                        v[q] = __hip_atomic_load(row + lane + (q << 6),
                                                 __ATOMIC_RELAXED, __HIP_MEMORY_SCOPE_AGENT);
                    bool ok = true;
#pragma unroll
                    for (int q = 0; q < 16; ++q)
                        ok &= ((unsigned)(v[q] >> 32) == want);
                    if (ok) break;
                }
#pragma unroll
                for (int q = 0; q < 16; ++q) {
                    union { unsigned u; float f; } cv;
                    cv.u = (unsigned)v[q];
                    h_lds[lane + (q << 6)] = cv.f;
                }
            }
        }
        __syncthreads();   // h_lds[t] ready; also orders prior step's LDS reads

        float gi = 0.f, gf = 0.f, gg = 0.f, go = 0.f;
#pragma unroll
        for (int k = 0; k < 4; ++k) {
            const float4 hv = *(const float4*)&h_lds[4 * (lane + (k << 6))];
            gi += w0[k].x * hv.x + w0[k].y * hv.y + w0[k].z * hv.z + w0[k].w * hv.w;
            gf += w1[k].x * hv.x + w1[k].y * hv.y + w1[k].z * hv.z + w1[k].w * hv.w;
            gg += w2[k].x * hv.x + w2[k].y * hv.y + w2[k].z * hv.z + w2[k].w * hv.w;
            go += w3[k].x * hv.x + w3[k].y * hv.y + w3[k].z * hv.z + w3[k].w * hv.w;
        }
#pragma unroll
        for (int d = 32; d > 0; d >>= 1) {
            gi += __shfl_xor(gi, d, 64);
            gf += __shfl_xor(gf, d, 64);
            gg += __shfl_xor(gg, d, 64);
            go += __shfl_xor(go, d, 64);
        }
        const float ig = sigmoidf_(gi + xb_i), fg = sigmoidf_(gf + xb_f), og = sigmoidf_(go + xb_o);
        const float gv = tanhf(gg + xb_g);
        c = fg * c + ig * gv;
        h_out = og * tanhf(c);

        if (lane == 0) {
            ys[(size_t)t * HDIM + j] = h_out;   // plain store (consumed post-kernel)
            union { float f; unsigned u; } hu; hu.f = h_out;
            const unsigned long long pk =
                ((unsigned long long)(tag_base + (unsigned)t + 1u) << 32) | (unsigned long long)hu.u;
            __hip_atomic_store(tagbuf + ((size_t)(t & 1) << 10) + j, pk,
                               __ATOMIC_RELAXED, __HIP_MEMORY_SCOPE_AGENT);
        }
    }
    if (lane == 0) { hN[j] = h_out; cN[j] = c; }
}

// ---------------------------------------------------------------------------
// Attention
// ---------------------------------------------------------------------------
__global__ __launch_bounds__(256) void attn_scores(
    const float* __restrict__ enc, const float* __restrict__ tgt,
    float* __restrict__ scores)
{
    const int lane = threadIdx.x & 63, wv = threadIdx.x >> 6;
    const int s = (blockIdx.x << 2) + wv;
    const float4* e4 = (const float4*)(enc + (size_t)s * HDIM);
    const float4* t4 = (const float4*)tgt;
    float acc = 0.f;
#pragma unroll
    for (int k = 0; k < 4; ++k) {
        const int idx = lane + (k << 6);
        const float4 e = e4[idx], t = t4[idx];
        acc += e.x * t.x + e.y * t.y + e.z * t.z + e.w * t.w;
    }
#pragma unroll
    for (int d = 32; d > 0; d >>= 1) acc += __shfl_xor(acc, d, 64);
    if (lane == 0) scores[s] = acc;
}

__global__ __launch_bounds__(1024) void attn_softmax(
    const float* __restrict__ scores, float* __restrict__ wts)
{
    __shared__ float rmax[16];
    __shared__ float rsum[16];
    const int tid = threadIdx.x, lane = tid & 63, wv = tid >> 6;
    const float4 v = ((const float4*)scores)[tid];
    float m = fmaxf(fmaxf(v.x, v.y), fmaxf(v.z, v.w));
#pragma unroll
    for (int d = 32; d > 0; d >>= 1) m = fmaxf(m, __shfl_xor(m, d, 64));
    if (lane == 0) rmax[wv] = m;
    __syncthreads();
    float gm = rmax[0];
#pragma unroll
    for (int i = 1; i < 16; ++i) gm = fmaxf(gm, rmax[i]);
    const float e0 = expf(v.x - gm), e1 = expf(v.y - gm), e2 = expf(v.z - gm), e3 = expf(v.w - gm);
    float s = e0 + e1 + e2 + e3;
#pragma unroll
    for (int d = 32; d > 0; d >>= 1) s += __shfl_xor(s, d, 64);
    if (lane == 0) rsum[wv] = s;
    __syncthreads();
    float gs = 0.f;
#pragma unroll
    for (int i = 0; i < 16; ++i) gs += rsum[i];
    const float inv = 1.0f / gs;
    ((float4*)wts)[tid] = make_float4(e0 * inv, e1 * inv, e2 * inv, e3 * inv);
}

__global__ __launch_bounds__(256) void attn_context(
    const float* __restrict__ wts, const float* __restrict__ enc,
    float* __restrict__ ctx)
{
    __shared__ float red[16][16];
    const int ci = threadIdx.x & 15, ri = threadIdx.x >> 4;
    const int col = blockIdx.x * 16 + ci;
    float acc = 0.f;
    for (int r = ri; r < SDIM; r += 16)
        acc += wts[r] * enc[(size_t)r * HDIM + col];
    red[ri][ci] = acc;
    __syncthreads();
    if (ri == 0) {
        float s = 0.f;
#pragma unroll
        for (int k = 0; k < 16; ++k) s += red[k][ci];
        ctx[col] = s;
    }
}

__global__ __launch_bounds__(256) void attn_final(
    const float* __restrict__ ctx, const float* __restrict__ h2,
    const float* __restrict__ w_cat, const float* __restrict__ b_cat,
    float* __restrict__ out)
{
    const int lane = threadIdx.x & 63, wv = threadIdx.x >> 6;
    const int j = (blockIdx.x << 2) + wv;
    const float4* wc1 = (const float4*)(w_cat + (size_t)j * 2048);
    const float4* wc2 = (const float4*)(w_cat + (size_t)j * 2048 + 1024);
    const float4* c4 = (const float4*)ctx;
    const float4* h4 = (const float4*)h2;
    float acc = 0.f;
#pragma unroll
    for (int k = 0; k < 4; ++k) {
        const int idx = lane + (k << 6);
        float4 a = wc1[idx], b = c4[idx];
        acc += a.x * b.x + a.y * b.y + a.z * b.z + a.w * b.w;
        a = wc2[idx]; b = h4[idx];
        acc += a.x * b.x + a.y * b.y + a.z * b.z + a.w * b.w;
    }
#pragma unroll
    for (int d = 32; d > 0; d >>= 1) acc += __shfl_xor(acc, d, 64);
    if (lane == 0) out[j] = tanhf(acc + b_cat[j]);
}

// ---------------------------------------------------------------------------
extern "C" void kernel_launch(void* const* d_in, const int* in_sizes, int n_in,
                              void* d_out, int out_size, void* d_ws, size_t ws_size,
                              hipStream_t stream)
{
    (void)in_sizes; (void)n_in; (void)out_size; (void)ws_size;
    const float* x     = (const float*)d_in[0];
    const float* enc   = (const float*)d_in[1];
    const float* h0all = (const float*)d_in[2];
    const float* c0all = (const float*)d_in[3];
    const float* w_ih0 = (const float*)d_in[4];
    const float* w_hh0 = (const float*)d_in[5];
    const float* b_ih0 = (const float*)d_in[6];
    const float* b_hh0 = (const float*)d_in[7];
    const float* w_ih1 = (const float*)d_in[8];
    const float* w_hh1 = (const float*)d_in[9];
    const float* b_ih1 = (const float*)d_in[10];
    const float* b_hh1 = (const float*)d_in[11];
    const float* w_cat = (const float*)d_in[12];
    const float* b_cat = (const float*)d_in[13];
    float* out = (float*)d_out;

    float* ws = (float*)d_ws;
    float* xg     = ws;                       // 1024*4096 = 4,194,304 floats
    float* out0   = ws + 4194304;             // 1024*1024 = 1,048,576
    float* scores = ws + 4194304 + 1048576;   // 4096
    float* wts    = scores + 4096;            // 4096
    float* ctx    = wts + 4096;               // 1024
    unsigned long long* tagbuf = (unsigned long long*)(ctx + 1024);  // [2][1024]

    float* out1 = out;                 // [1024][1024]
    float* hN   = out + 1048576;       // h1, h2
    float* cN   = out + 1050624;       // c1, c2
    float* attn = out + 1052672;       // 1024

    hipMemsetAsync(tagbuf, 0, 2048 * sizeof(unsigned long long), stream);

    dim3 gg(64, 16);  // N/64, M/64
    gemm_xg<<<gg, 256, 0, stream>>>(x, w_ih0, b_ih0, b_hh0, xg, 1024, 4096, 1024);
    lstm_scan<<<NBLK, 256, 0, stream>>>(xg, w_hh0, h0all, c0all, out0, hN, cN,
                                        tagbuf, 0u);
    gemm_xg<<<gg, 256, 0, stream>>>(out0, w_ih1, b_ih1, b_hh1, xg, 1024, 4096, 1024);
    lstm_scan<<<NBLK, 256, 0, stream>>>(xg, w_hh1, h0all + 1024, c0all + 1024,
                                        out1, hN + 1024, cN + 1024,
                                        tagbuf, (unsigned)T_STEPS);
    attn_scores<<<1024, 256, 0, stream>>>(enc, hN + 1024, scores);
    attn_softmax<<<1, 1024, 0, stream>>>(scores, wts);
    attn_context<<<64, 256, 0, stream>>>(wts, enc, ctx);
    attn_final<<<256, 256, 0, stream>>>(ctx, hN + 1024, w_cat, b_cat, attn);
}